// Round 1
// baseline (946.319 us; speedup 1.0000x reference)
//
#include <hip/hip_runtime.h>

#define NN 50000
#define NE 800000
#define EP (NE + NN)      // edges + self loops
#define HID 128
#define FIN 64
#define NG 64
#define SLOPE 0.2f

__device__ __forceinline__ float wred_sum(float v) {
  for (int off = 32; off; off >>= 1) v += __shfl_xor(v, off);
  return v;
}
__device__ __forceinline__ float wred_max(float v) {
  for (int off = 32; off; off >>= 1) v = fmaxf(v, __shfl_xor(v, off));
  return v;
}

// ---- mean of edge weights -------------------------------------------------
__global__ void k_mean(const float* __restrict__ ew, float* __restrict__ meansum) {
  int tid = blockIdx.x * blockDim.x + threadIdx.x;
  int stride = gridDim.x * blockDim.x;
  float s = 0.f;
  for (int i = tid; i < NE; i += stride) s += ew[i];
  s = wred_sum(s);
  if ((threadIdx.x & 63) == 0) atomicAdd(meansum, s);
}

// ---- histogram of destinations (incl self loops) --------------------------
__global__ void k_hist(const int* __restrict__ edst, int* __restrict__ counts) {
  int tid = blockIdx.x * blockDim.x + threadIdx.x;
  int stride = gridDim.x * blockDim.x;
  for (int i = tid; i < EP; i += stride) {
    int d = (i < NE) ? edst[i] : (i - NE);
    atomicAdd(&counts[d], 1);
  }
}

// ---- single-block exclusive scan; also zeroes counts (reused as cursor) ---
__global__ void k_scan(int* __restrict__ counts, int* __restrict__ starts) {
  __shared__ int wsum[16];
  __shared__ int woff[16];
  int t = threadIdx.x;
  int lane = t & 63;
  int w = t >> 6;
  int carry = 0;
  for (int base = 0; base < NN; base += 1024) {
    int i = base + t;
    int v = (i < NN) ? counts[i] : 0;
    if (i < NN) counts[i] = 0;   // reset cursor for scatter
    int sc = v;
    #pragma unroll
    for (int d = 1; d < 64; d <<= 1) {
      int u = __shfl_up(sc, d);
      if (lane >= d) sc += u;
    }
    if (lane == 63) wsum[w] = sc;
    __syncthreads();
    if (w == 0 && lane < 16) {
      int x = wsum[lane];
      #pragma unroll
      for (int d = 1; d < 16; d <<= 1) {
        int u = __shfl_up(x, d);
        if (lane >= d) x += u;
      }
      woff[lane] = x;   // inclusive scan of wave sums
    }
    __syncthreads();
    int waveoff = (w == 0) ? 0 : woff[w - 1];
    if (i < NN) starts[i] = carry + waveoff + sc - v;
    carry += woff[15];
    __syncthreads();   // protect wsum/woff before next chunk
  }
  if (t == 0) starts[NN] = carry;
}

// ---- scatter edges into dst-sorted order ----------------------------------
__global__ void k_scatter(const int* __restrict__ esrc, const int* __restrict__ edst,
                          const float* __restrict__ ew, const float* __restrict__ meansum,
                          const int* __restrict__ starts, int* __restrict__ cursor,
                          int* __restrict__ srcs, int* __restrict__ dsts,
                          float* __restrict__ wgts) {
  float mw = meansum[0] * (1.0f / NE);
  int tid = blockIdx.x * blockDim.x + threadIdx.x;
  int stride = gridDim.x * blockDim.x;
  for (int i = tid; i < EP; i += stride) {
    int s, d; float wv;
    if (i < NE) { s = esrc[i]; d = edst[i]; wv = ew[i]; }
    else        { s = d = i - NE; wv = mw; }
    int pos = starts[d] + atomicAdd(&cursor[d], 1);
    srcs[pos] = s; dsts[pos] = d; wgts[pos] = wv;
  }
}

// ---- fp32 GEMM: C[n x 128] = A[n x K] @ W[K x 128] + b --------------------
template <int K>
__global__ __launch_bounds__(256) void k_gemm(const float* __restrict__ A,
                                              const float* __restrict__ W,
                                              const float* __restrict__ b,
                                              float* __restrict__ C, int n) {
  __shared__ float As[64][K];
  int t = threadIdx.x;
  int nb = blockIdx.x * 64;
  constexpr int F4 = 16 * K;     // float4 count in the A tile
  for (int i = t; i < F4; i += 256) {
    int row = i / (K / 4);
    int c = (i % (K / 4)) * 4;
    int gn = nb + row;
    float4 v = make_float4(0.f, 0.f, 0.f, 0.f);
    if (gn < n) v = *(const float4*)(A + (size_t)gn * K + c);
    *(float4*)&As[row][c] = v;
  }
  __syncthreads();
  int fx = (t & 31) * 4;
  int ny = (t >> 5) * 8;
  float acc[8][4] = {};
  for (int k = 0; k < K; ++k) {
    float4 wv = *(const float4*)(W + (size_t)k * HID + fx);
    #pragma unroll
    for (int j = 0; j < 8; ++j) {
      float a = As[ny + j][k];
      acc[j][0] += a * wv.x; acc[j][1] += a * wv.y;
      acc[j][2] += a * wv.z; acc[j][3] += a * wv.w;
    }
  }
  float4 bb = *(const float4*)(b + fx);
  #pragma unroll
  for (int j = 0; j < 8; ++j) {
    int gn = nb + ny + j;
    if (gn < n) {
      float4 o = make_float4(acc[j][0] + bb.x, acc[j][1] + bb.y,
                             acc[j][2] + bb.z, acc[j][3] + bb.w);
      *(float4*)(C + (size_t)gn * HID + fx) = o;
    }
  }
}

// ---- per-edge attention logits (wave per edge) ----------------------------
__global__ void k_logits(const float* __restrict__ xl, const float* __restrict__ xr,
                         const int* __restrict__ srcs, const int* __restrict__ dsts,
                         const float* __restrict__ wgts, const float* __restrict__ We,
                         const float* __restrict__ att, float* __restrict__ logits) {
  int gtid = blockIdx.x * blockDim.x + threadIdx.x;
  int wave = gtid >> 6;
  int lane = gtid & 63;
  int nw = (gridDim.x * blockDim.x) >> 6;
  int f = lane * 2;
  float we0 = We[f], we1 = We[f + 1];
  float at0 = att[f], at1 = att[f + 1];
  for (int p = wave; p < EP; p += nw) {
    int s = srcs[p], d = dsts[p];
    float wv = wgts[p];
    float2 a = *(const float2*)(xl + (size_t)s * HID + f);
    float2 b = *(const float2*)(xr + (size_t)d * HID + f);
    float v0 = a.x + b.x + wv * we0;
    float v1 = a.y + b.y + wv * we1;
    v0 = v0 > 0.f ? v0 : SLOPE * v0;
    v1 = v1 > 0.f ? v1 : SLOPE * v1;
    float part = wred_sum(v0 * at0 + v1 * at1);
    if (lane == 0) logits[p] = part;
  }
}

// ---- per-node softmax + aggregation (wave per node) -----------------------
// PHASE 0: write h = relu(agg + bias).  PHASE 1: pool into per-graph sums.
template <int PHASE>
__global__ void k_agg(const float* __restrict__ xl, const float* __restrict__ logits,
                      const int* __restrict__ srcs, const int* __restrict__ starts,
                      const float* __restrict__ bias, float* __restrict__ hout,
                      const int* __restrict__ batch, float* __restrict__ pool_sums,
                      float* __restrict__ pool_cnt) {
  int node = blockIdx.x * (blockDim.x >> 6) + (threadIdx.x >> 6);
  int lane = threadIdx.x & 63;
  if (node >= NN) return;
  int s0 = starts[node], s1 = starts[node + 1];
  float m = -1e30f;
  for (int i = s0 + lane; i < s1; i += 64) m = fmaxf(m, logits[i]);
  m = wred_max(m);
  int f = lane * 2;
  float ssum = 0.f, a0 = 0.f, a1 = 0.f;
  for (int i0 = s0; i0 < s1; i0 += 64) {
    int i = i0 + lane;
    float w = 0.f; int sreg = 0;
    if (i < s1) { w = __expf(logits[i] - m); sreg = srcs[i]; }
    ssum += w;
    int cnt = min(64, s1 - i0);
    for (int j = 0; j < cnt; ++j) {
      float wj = __shfl(w, j);
      int sj = __shfl(sreg, j);
      float2 v = *(const float2*)(xl + (size_t)sj * HID + f);
      a0 += wj * v.x; a1 += wj * v.y;
    }
  }
  ssum = wred_sum(ssum);
  float inv = 1.0f / ssum;
  a0 = fmaxf(a0 * inv + bias[f], 0.f);
  a1 = fmaxf(a1 * inv + bias[f + 1], 0.f);
  if (PHASE == 0) {
    *(float2*)(hout + (size_t)node * HID + f) = make_float2(a0, a1);
  } else {
    int g = batch[node];
    atomicAdd(&pool_sums[g * HID + f], a0);
    atomicAdd(&pool_sums[g * HID + f + 1], a1);
    if (lane == 0) atomicAdd(&pool_cnt[g], 1.f);
  }
}

// ---- pooled @ Wlin + blin -------------------------------------------------
__global__ void k_final(const float* __restrict__ pool_sums, const float* __restrict__ pool_cnt,
                        const float* __restrict__ Wlin, const float* __restrict__ blin,
                        float* __restrict__ out) {
  int wid = (blockIdx.x * blockDim.x + threadIdx.x) >> 6;
  int lane = threadIdx.x & 63;
  if (wid >= NG) return;
  int f = lane * 2;
  float2 s = *(const float2*)(pool_sums + (size_t)wid * HID + f);
  float part = s.x * Wlin[f] + s.y * Wlin[f + 1];
  part = wred_sum(part);
  if (lane == 0) {
    float cnt = fmaxf(pool_cnt[wid], 1.f);
    out[wid] = part / cnt + blin[0];
  }
}

extern "C" void kernel_launch(void* const* d_in, const int* in_sizes, int n_in,
                              void* d_out, int out_size, void* d_ws, size_t ws_size,
                              hipStream_t stream) {
  const float* x     = (const float*)d_in[0];
  const int*   ei    = (const int*)d_in[1];      // [2][NE]
  const float* ew    = (const float*)d_in[2];
  const int*   batch = (const int*)d_in[3];
  const float* W1l = (const float*)d_in[4];
  const float* b1l = (const float*)d_in[5];
  const float* W1r = (const float*)d_in[6];
  const float* b1r = (const float*)d_in[7];
  const float* We1 = (const float*)d_in[8];
  const float* at1 = (const float*)d_in[9];
  const float* bi1 = (const float*)d_in[10];
  const float* W2l = (const float*)d_in[11];
  const float* b2l = (const float*)d_in[12];
  const float* W2r = (const float*)d_in[13];
  const float* b2r = (const float*)d_in[14];
  const float* We2 = (const float*)d_in[15];
  const float* at2 = (const float*)d_in[16];
  const float* bi2 = (const float*)d_in[17];
  const float* Wlin = (const float*)d_in[18];
  const float* blin = (const float*)d_in[19];

  float* ws = (float*)d_ws;
  size_t o = 0;
  float* xl     = ws + o; o += (size_t)NN * HID;
  float* xr     = ws + o; o += (size_t)NN * HID;
  float* hb     = ws + o; o += (size_t)NN * HID;
  float* logits = ws + o; o += EP;
  float* wgts   = ws + o; o += EP;
  int*   srcs   = (int*)(ws + o); o += EP;
  int*   dsts   = (int*)(ws + o); o += EP;
  int*   starts = (int*)(ws + o); o += NN + 1;
  size_t zoff = o;
  int*   counts    = (int*)(ws + o); o += NN;
  float* meansum   = ws + o; o += 1;
  float* pool_sums = ws + o; o += (size_t)NG * HID;
  float* pool_cnt  = ws + o; o += NG;
  size_t zero_bytes = (o - zoff) * sizeof(float);

  hipMemsetAsync(counts, 0, zero_bytes, stream);

  // build dst-sorted CSR (shared by both layers)
  k_mean<<<256, 256, 0, stream>>>(ew, meansum);
  k_hist<<<1024, 256, 0, stream>>>(ei + NE, counts);
  k_scan<<<1, 1024, 0, stream>>>(counts, starts);
  k_scatter<<<1024, 256, 0, stream>>>(ei, ei + NE, ew, meansum, starts, counts,
                                      srcs, dsts, wgts);

  int gb = (NN + 63) / 64;
  // layer 1
  k_gemm<FIN><<<gb, 256, 0, stream>>>(x, W1l, b1l, xl, NN);
  k_gemm<FIN><<<gb, 256, 0, stream>>>(x, W1r, b1r, xr, NN);
  k_logits<<<4096, 256, 0, stream>>>(xl, xr, srcs, dsts, wgts, We1, at1, logits);
  k_agg<0><<<NN / 4, 256, 0, stream>>>(xl, logits, srcs, starts, bi1, hb,
                                       nullptr, nullptr, nullptr);
  // layer 2
  k_gemm<HID><<<gb, 256, 0, stream>>>(hb, W2l, b2l, xl, NN);
  k_gemm<HID><<<gb, 256, 0, stream>>>(hb, W2r, b2r, xr, NN);
  k_logits<<<4096, 256, 0, stream>>>(xl, xr, srcs, dsts, wgts, We2, at2, logits);
  k_agg<1><<<NN / 4, 256, 0, stream>>>(xl, logits, srcs, starts, bi2, nullptr,
                                       batch, pool_sums, pool_cnt);
  // head
  k_final<<<16, 256, 0, stream>>>(pool_sums, pool_cnt, Wlin, blin, (float*)d_out);
}